// Round 6
// baseline (183.432 us; speedup 1.0000x reference)
//
#include <hip/hip_runtime.h>
#include <hip/hip_bf16.h>
#include <math.h>

#define NB 8192        // batch
#define ND 256         // z dim
#define NSCORE 32      // binding dim
#define NSTRIPE 8      // j-stripes for nearest-neighbor minima (1024 j each)
#define NBLK (NB / 128)                  // 64
#define NTILE (NBLK * (NBLK + 1) / 2)    // 2080 upper-triangular tiles

typedef __attribute__((ext_vector_type(8))) short bf16x8;
typedef __attribute__((ext_vector_type(4))) float f32x4;
typedef unsigned long long u64;

#define U64MAX 0xFFFFFFFFFFFFFFFFull

#define GLOBAL_LOAD_LDS16(gptr, lptr) \
  __builtin_amdgcn_global_load_lds((const __attribute__((address_space(1))) void*)(gptr), \
                                   (__attribute__((address_space(3))) void*)(lptr), 16, 0, 0)

__device__ __forceinline__ float bf2f(ushort u) {
  union { unsigned int ui; float f; } c;
  c.ui = ((unsigned int)u) << 16;
  return c.f;
}

__device__ __forceinline__ u64 shfl_xor_u64(u64 v, int m) {
  unsigned int lo = (unsigned int)v, hi = (unsigned int)(v >> 32);
  lo = __shfl_xor(lo, m);
  hi = __shfl_xor(hi, m);
  return ((u64)hi << 32) | lo;
}

// decode linear idx -> (bi <= bj) upper-triangular pair; idx = bj*(bj+1)/2 + bi
__device__ __forceinline__ void tri_decode(int idx, int& bi, int& bj) {
  float fj = (sqrtf(8.0f * (float)idx + 1.0f) - 1.0f) * 0.5f;
  int j = (int)fj;
  if ((j + 1) * (j + 2) / 2 <= idx) ++j;
  else if (j * (j + 1) / 2 > idx) --j;
  bj = j;
  bi = idx - j * (j + 1) / 2;
}

// ---------------- K0: prep — normalize z, bs norms/bf16, all inits ----------
// acc2[0] = uniformity accumulator, acc2[1] = info accumulator.
__global__ __launch_bounds__(256) void k_prep(const float* __restrict__ z,
                                              const float* __restrict__ bs,
                                              ushort* __restrict__ znb,
                                              ushort* __restrict__ bsb,
                                              float* __restrict__ bsq,
                                              float* __restrict__ rowsum,
                                              u64* __restrict__ minu,
                                              float* __restrict__ acc2) {
  const int i = blockIdx.x;
  const int t = threadIdx.x;
  const float v = z[(size_t)i * ND + t];
  float s = v * v;
  #pragma unroll
  for (int m = 32; m >= 1; m >>= 1) s += __shfl_xor(s, m);
  __shared__ float wsum[4];
  if ((t & 63) == 0) wsum[t >> 6] = s;
  __syncthreads();
  s = wsum[0] + wsum[1] + wsum[2] + wsum[3];
  const float nv = v / sqrtf(s);
  const __hip_bfloat16 hb = __float2bfloat16(nv);
  znb[(size_t)i * ND + t] = *(const ushort*)&hb;
  if (t < NSCORE) {
    const float bv = bs[(size_t)i * NSCORE + t];
    const __hip_bfloat16 bh = __float2bfloat16(bv);
    bsb[(size_t)i * NSCORE + t] = *(const ushort*)&bh;
    float q = bv * bv;
    #pragma unroll
    for (int m = 16; m >= 1; m >>= 1) q += __shfl_xor(q, m, 32);
    if (t == 0) bsq[i] = q;
  }
  if (t >= 64 && t < 64 + NSTRIPE) minu[(size_t)i * NSTRIPE + (t - 64)] = U64MAX;
  if (t == 96) rowsum[i] = 0.f;
  if (i == 0 && t == 97) { acc2[0] = 0.f; acc2[1] = 0.f; }
}

// ---------------- K1: fused tile pass — nn minima + sim GEMM ----------------
// Per upper-triangular 128x128 tile (bi<=bj):
//  Phase A (nn): one K=32 MFMA set on bs panels; symmetric key
//    d2 = bsq_i + bsq_j - 2*dot. Row-mins -> minu[stripe(bj)][i]; col-mins
//    (bi!=bj) -> minu[stripe(bi)][j]. Packed u64 (f32bits(d2+1024)<<32 | idx).
//  Phase B (sim): 8-chunk K-loop bf16 MFMA on zn panels; rowsum via
//    exp(sim/tau) row+col sums (colsum = mirror tile's rowsum); uniformity
//    exp(-2*max(0,2-2*sim)) x2 off-diagonal -> scalar atomicAdd.
__global__ __launch_bounds__(256) void k_tile(const ushort* __restrict__ znb,
                                              const ushort* __restrict__ bsb,
                                              const float* __restrict__ bsq,
                                              float* __restrict__ rowsum,
                                              u64* __restrict__ minu,
                                              float* __restrict__ acc2) {
  __shared__ ushort PA[128 * 32];  // bs i-panel (8 KB)
  __shared__ ushort PB[128 * 32];  // bs j-panel (8 KB)
  __shared__ ushort ZA[128 * 32];  // zn i-panel chunk (8 KB)
  __shared__ ushort ZB[128 * 32];  // zn j-panel chunk (8 KB)
  int bi, bj; tri_decode(blockIdx.x, bi, bj);
  const int t = threadIdx.x;
  const int w = t >> 6, l = t & 63;
  const int quad = l >> 4, m16 = l & 15;
  const int i0 = bi * 128, j0 = bj * 128;
  const int wm = w >> 1, wn = w & 1;

  // staging geometry: wave w covers LDS bytes [w*2048, w*2048+2048) per panel
  const int srow = w * 32 + (l >> 2);
  const int skb = (l & 3) * 16;

  // prologue: stage bs panels + zn chunk 0
  #pragma unroll
  for (int s = 0; s < 2; ++s) {
    const int ra = i0 + srow + s * 16, rb = j0 + srow + s * 16;
    GLOBAL_LOAD_LDS16((const char*)bsb + (size_t)ra * (NSCORE * 2) + skb, (char*)PA + w * 2048 + s * 1024);
    GLOBAL_LOAD_LDS16((const char*)bsb + (size_t)rb * (NSCORE * 2) + skb, (char*)PB + w * 2048 + s * 1024);
    GLOBAL_LOAD_LDS16((const char*)znb + (size_t)ra * (ND * 2) + skb,     (char*)ZA + w * 2048 + s * 1024);
    GLOBAL_LOAD_LDS16((const char*)znb + (size_t)rb * (ND * 2) + skb,     (char*)ZB + w * 2048 + s * 1024);
  }
  __syncthreads();

  // ---- Phase A: nearest-neighbor minima (strip-wise, low register use) ----
  {
    const int stripe_i = bi >> 3, stripe_j = bj >> 3;
    const int jbase = j0 + wn * 64 + m16;
    bf16x8 nb[4];
    #pragma unroll
    for (int nt = 0; nt < 4; ++nt)
      nb[nt] = *(const bf16x8*)&PB[(wn * 64 + nt * 16 + m16) * 32 + quad * 8];
    float bq[4];
    #pragma unroll
    for (int nt = 0; nt < 4; ++nt) bq[nt] = bsq[jbase + nt * 16];
    u64 cbest[4] = {U64MAX, U64MAX, U64MAX, U64MAX};
    #pragma unroll
    for (int mt = 0; mt < 4; ++mt) {
      const bf16x8 na = *(const bf16x8*)&PA[(wm * 64 + mt * 16 + m16) * 32 + quad * 8];
      f32x4 nc[4];
      #pragma unroll
      for (int nt = 0; nt < 4; ++nt) {
        nc[nt] = (f32x4){0.f, 0.f, 0.f, 0.f};
        nc[nt] = __builtin_amdgcn_mfma_f32_16x16x32_bf16(na, nb[nt], nc[nt], 0, 0, 0);
      }
      const float4 rq = *(const float4*)&bsq[i0 + wm * 64 + mt * 16 + quad * 4];
      const float rqa[4] = {rq.x, rq.y, rq.z, rq.w};
      u64 rbest[4] = {U64MAX, U64MAX, U64MAX, U64MAX};
      #pragma unroll
      for (int reg = 0; reg < 4; ++reg) {
        const int row = i0 + wm * 64 + mt * 16 + quad * 4 + reg;
        #pragma unroll
        for (int nt = 0; nt < 4; ++nt) {
          const float d2 = rqa[reg] + bq[nt] - 2.0f * nc[nt][reg];
          union { float f; unsigned int u; } c; c.f = d2 + 1024.0f;  // always > 0
          const u64 hib = (u64)c.u << 32;
          const u64 pr = hib | (unsigned int)(jbase + nt * 16);
          rbest[reg] = (pr < rbest[reg]) ? pr : rbest[reg];
          const u64 pc = hib | (unsigned int)row;
          cbest[nt] = (pc < cbest[nt]) ? pc : cbest[nt];
        }
      }
      // batched level-major reduce over the 16 cols (4 independent chains)
      #pragma unroll
      for (int m = 1; m <= 8; m <<= 1)
        #pragma unroll
        for (int reg = 0; reg < 4; ++reg) {
          const u64 o = shfl_xor_u64(rbest[reg], m);
          rbest[reg] = (o < rbest[reg]) ? o : rbest[reg];
        }
      if (m16 == 0)
        #pragma unroll
        for (int reg = 0; reg < 4; ++reg)
          atomicMin(&minu[(size_t)stripe_j * NB + i0 + wm * 64 + mt * 16 + quad * 4 + reg], rbest[reg]);
    }
    if (bi != bj) {
      #pragma unroll
      for (int m = 16; m <= 32; m <<= 1)
        #pragma unroll
        for (int nt = 0; nt < 4; ++nt) {
          const u64 o = shfl_xor_u64(cbest[nt], m);
          cbest[nt] = (o < cbest[nt]) ? o : cbest[nt];
        }
      if (quad == 0)
        #pragma unroll
        for (int nt = 0; nt < 4; ++nt)
          atomicMin(&minu[(size_t)stripe_i * NB + jbase + nt * 16], cbest[nt]);
    }
  }

  // ---- Phase B: sim GEMM mainloop (chunk 0 already staged) ----
  f32x4 acc[4][4];
  #pragma unroll
  for (int mt = 0; mt < 4; ++mt)
    #pragma unroll
    for (int nt = 0; nt < 4; ++nt) acc[mt][nt] = (f32x4){0.f, 0.f, 0.f, 0.f};

  for (int kci = 0; kci < ND / 32; ++kci) {
    bf16x8 a[4], b[4];
    #pragma unroll
    for (int mt = 0; mt < 4; ++mt)
      a[mt] = *(const bf16x8*)&ZA[(wm * 64 + mt * 16 + m16) * 32 + quad * 8];
    #pragma unroll
    for (int nt = 0; nt < 4; ++nt)
      b[nt] = *(const bf16x8*)&ZB[(wn * 64 + nt * 16 + m16) * 32 + quad * 8];
    #pragma unroll
    for (int mt = 0; mt < 4; ++mt)
      #pragma unroll
      for (int nt = 0; nt < 4; ++nt)
        acc[mt][nt] = __builtin_amdgcn_mfma_f32_16x16x32_bf16(a[mt], b[nt], acc[mt][nt], 0, 0, 0);
    if (kci < ND / 32 - 1) {
      __syncthreads();  // all waves done reading this chunk
      const int kb = (kci + 1) * 64;  // byte offset of next chunk in a zn row
      #pragma unroll
      for (int s = 0; s < 2; ++s) {
        const int ra = i0 + srow + s * 16, rb = j0 + srow + s * 16;
        GLOBAL_LOAD_LDS16((const char*)znb + (size_t)ra * (ND * 2) + kb + skb, (char*)ZA + w * 2048 + s * 1024);
        GLOBAL_LOAD_LDS16((const char*)znb + (size_t)rb * (ND * 2) + kb + skb, (char*)ZB + w * 2048 + s * 1024);
      }
      __syncthreads();  // staging complete
    }
  }

  // epilogue: C layout col=lane&15, row=quad*4+reg (m89-verified)
  const float C1 = 14.426950408889634f;  // log2(e)/tau
  const float C2 = 5.770780163555854f;   // 4*log2(e)
  float usum = 0.f;
  float cs[4] = {0.f, 0.f, 0.f, 0.f};
  #pragma unroll
  for (int mt = 0; mt < 4; ++mt) {
    float rs[4] = {0.f, 0.f, 0.f, 0.f};
    #pragma unroll
    for (int reg = 0; reg < 4; ++reg) {
      #pragma unroll
      for (int nt = 0; nt < 4; ++nt) {
        const float s = acc[mt][nt][reg];
        const float e = exp2f(s * C1);             // exp(sim/tau), computed once
        rs[reg] += e;
        cs[nt] += e;
        usum += exp2f(fminf(0.f, (s - 1.f) * C2)); // exp(-2*max(0,2-2*sim))
      }
    }
    #pragma unroll
    for (int m = 1; m <= 8; m <<= 1)
      #pragma unroll
      for (int reg = 0; reg < 4; ++reg) rs[reg] += __shfl_xor(rs[reg], m);
    if (m16 == 0)
      #pragma unroll
      for (int reg = 0; reg < 4; ++reg)
        atomicAdd(&rowsum[i0 + wm * 64 + mt * 16 + quad * 4 + reg], rs[reg]);
  }
  if (bi != bj) {
    #pragma unroll
    for (int m = 16; m <= 32; m <<= 1)
      #pragma unroll
      for (int nt = 0; nt < 4; ++nt) cs[nt] += __shfl_xor(cs[nt], m);
    if (quad == 0)
      #pragma unroll
      for (int nt = 0; nt < 4; ++nt)
        atomicAdd(&rowsum[j0 + wn * 64 + nt * 16 + m16], cs[nt]);
  }
  #pragma unroll
  for (int m = 32; m >= 1; m >>= 1) usum += __shfl_xor(usum, m);
  __shared__ float wred[4];
  if (l == 0) wred[w] = usum;
  __syncthreads();
  if (t == 0)
    atomicAdd(&acc2[0], (wred[0] + wred[1] + wred[2] + wred[3]) * ((bi != bj) ? 2.f : 1.f));
}

// ---------------- K2: select 5-of-8 stripe minima + info accumulation -------
// One wave per row (4 waves/block). Self candidate dropped by index.
// rowsum is final here -> fold the per-row info term and accumulate.
__global__ __launch_bounds__(256) void k_sel(const u64* __restrict__ minu,
                                             const ushort* __restrict__ znb,
                                             const float* __restrict__ rowsum,
                                             float* __restrict__ acc2) {
  __shared__ int sel[4][5];
  __shared__ float ired[4];
  const int t = threadIdx.x;
  const int w = t >> 6, l = t & 63;
  const int i = blockIdx.x * 4 + w;
  u64 c = U64MAX;
  if (l < NSTRIPE) {
    c = minu[(size_t)l * NB + i];
    if ((int)(c & 0xFFFFFFFFu) == i) c = U64MAX;  // drop self
  }
  for (int r = 0; r < 5; ++r) {
    u64 v = c;
    #pragma unroll
    for (int m = 1; m <= 4; m <<= 1) {
      const u64 o = shfl_xor_u64(v, m);
      v = (o < v) ? o : v;
    }
    const int jmin = (int)(__shfl(v, 0) & 0xFFFFFFFFu);
    if (l == 0) sel[w][r] = jmin;
    if (c == __shfl(v, 0)) c = U64MAX;  // retire winner (distinct idx => unique)
  }
  const ushort4 zi4 = *(const ushort4*)(znb + (size_t)i * ND + l * 4);
  const float zix = bf2f(zi4.x), ziy = bf2f(zi4.y), ziz = bf2f(zi4.z), ziw = bf2f(zi4.w);
  float ps = 0.f;
  #pragma unroll
  for (int cix = 0; cix < 5; ++cix) {
    const int j = sel[w][cix];
    const ushort4 zj4 = *(const ushort4*)(znb + (size_t)j * ND + l * 4);
    float d = zix * bf2f(zj4.x) + ziy * bf2f(zj4.y) + ziz * bf2f(zj4.z) + ziw * bf2f(zj4.w);
    #pragma unroll
    for (int m = 32; m >= 1; m >>= 1) d += __shfl_xor(d, m);
    ps += d;
  }
  if (l == 0) ired[w] = logf(rowsum[i] + 1e-8f) - ps * 2.0f;  // ps*0.2 (mean) * 10 (1/tau)
  __syncthreads();
  if (t == 0) atomicAdd(&acc2[1], ired[0] + ired[1] + ired[2] + ired[3]);
}

// ---------------- K3: final scalar combine ----------------
__global__ void k_fin(const float* __restrict__ acc2, float* __restrict__ out) {
  if (threadIdx.x == 0) {
    const float l_info = acc2[1] / (float)NB;
    const float l_unif = logf(acc2[0] / ((float)NB * (float)NB) + 1e-8f);
    out[0] = l_info + 0.1f * l_unif;
  }
}

extern "C" void kernel_launch(void* const* d_in, const int* in_sizes, int n_in,
                              void* d_out, int out_size, void* d_ws, size_t ws_size,
                              hipStream_t stream) {
  const float* z  = (const float*)d_in[0];
  const float* bs = (const float*)d_in[1];
  float* out = (float*)d_out;

  // workspace layout (~5.1 MB, all offsets 8B-aligned)
  ushort* znb    = (ushort*)d_ws;                        // 8192*256 bf16 (4 MB)
  ushort* bsb    = znb + (size_t)NB * ND;                // 8192*32 bf16 (512 KB)
  float*  bsq    = (float*)(bsb + (size_t)NB * NSCORE);  // 8192 (32 KB)
  float*  rowsum = bsq + NB;                             // 8192 (32 KB)
  float*  acc2   = rowsum + NB;                          // 2 floats
  u64*    minu   = (u64*)(acc2 + 2);                     // 8*8192 u64 (512 KB)

  k_prep<<<NB, 256, 0, stream>>>(z, bs, znb, bsb, bsq, rowsum, minu, acc2);
  k_tile<<<NTILE, 256, 0, stream>>>(znb, bsb, bsq, rowsum, minu, acc2);
  k_sel<<<NB / 4, 256, 0, stream>>>(minu, znb, rowsum, acc2);
  k_fin<<<1, 64, 0, stream>>>(acc2, out);
}